// Round 6
// baseline (102.401 us; speedup 1.0000x reference)
//
#include <hip/hip_runtime.h>
#include <stdint.h>
#include <math.h>

// Problem constants (fixed by the reference)
#define DDIM    20
#define SLATE   5
#define KSEL    100
#define HID     256
#define SAMPN   16384                // prefix-sample size (docs are iid)
#define NSH     8                    // atomic shards
#define SHCAP   1024                 // per-shard candidate capacity
#define RCAP    8192                 // recovery scratch per slate (8 slices x 1024)
#define STP     128                  // shard-top stride (pad of KSEL)
#define OUT_IDX_OFF (SLATE * KSEL * DDIM)   // 10000

// Workspace byte offsets
#define WS_PROTO   0                 // f64[100]
#define WS_PROTOF  1024              // f32[100]
#define WS_TP2     1536              // u16[5]  T10+2
#define WS_TM2     1556              // u16[5]  T10-2
#define WS_THI     1576              // u16[5]  sample rank-100 key
#define WS_SHCNT   1600              // u32[40] stride-16 (64B lines)  <- zeroed in head
#define WS_STRICT  4160              // u32[40] stride-16              <- zeroed
#define WS_CNT2    6720              // u32[5]  stride-16 (unused)     <- zeroed
#define WS_ZEND    7040              // end of zeroed region
#define WS_SKEYS   8192              // (unused since R5 — skeys register-resident)
#define WS_CAND    172032            // u32[5][NSH][SHCAP]           -> 335872
#define WS_CAND2   335872            // u32[5][NSH][1024] recovery   -> 499712
#define WS_STD2    499712            // f64[5][NSH][STP]             -> 540672
#define WS_STIX    540672            // u32[5][NSH][STP]             -> 561152
#define WS_STLEN   561152            // u32[5][NSH]                  -> 561312

// ---- exact-order f64 distance: UNCHANGED from all passing rounds ----
__device__ __forceinline__ double dleaky(double x) { return x >= 0.0 ? x : 0.01 * x; }

__device__ __forceinline__ double calc_d2(const float* doc, const double* p) {
    double acc = 0.0;
#pragma unroll
    for (int i = 0; i < DDIM; ++i) {
        double d = (double)doc[i] - p[i];
        acc = fma(d, d, acc);
    }
    return acc;
}

__device__ __forceinline__ void load_doc(const float* __restrict__ docs,
                                         size_t n, float* doc) {
    const float4* dp = (const float4*)(docs + n * DDIM);
    float4 v0 = dp[0], v1 = dp[1], v2 = dp[2], v3 = dp[3], v4 = dp[4];
    doc[0] = v0.x; doc[1] = v0.y; doc[2] = v0.z; doc[3] = v0.w;
    doc[4] = v1.x; doc[5] = v1.y; doc[6] = v1.z; doc[7] = v1.w;
    doc[8] = v2.x; doc[9] = v2.y; doc[10] = v2.z; doc[11] = v2.w;
    doc[12] = v3.x; doc[13] = v3.y; doc[14] = v3.z; doc[15] = v3.w;
    doc[16] = v4.x; doc[17] = v4.y; doc[18] = v4.z; doc[19] = v4.w;
}

// Row-dot in f64 with EXPLICIT 8x-float4 load batches: 32 floats in flight
// per latency stop (R5 lesson: rolled scalar-load loops at 36 VGPR serialize
// to ~500cy/element). FMA order i=0..255 strictly ascending — bit-identical
// to all passing rounds.
__device__ __forceinline__ double dot256_f64(const float* __restrict__ Wrow,
                                             const double* __restrict__ h) {
    const float4* wr = (const float4*)Wrow;     // row is 1KB, 16B-aligned
    double acc = 0.0;
#pragma unroll
    for (int b = 0; b < 8; ++b) {
        float4 v[8];
#pragma unroll
        for (int u = 0; u < 8; ++u) v[u] = wr[b * 8 + u];   // 8 independent loads
#pragma unroll
        for (int u = 0; u < 8; ++u) {
            const int i = (b * 8 + u) * 4;
            acc = fma(h[i + 0], (double)v[u].x, acc);
            acc = fma(h[i + 1], (double)v[u].y, acc);
            acc = fma(h[i + 2], (double)v[u].z, acc);
            acc = fma(h[i + 3], (double)v[u].w, acc);
        }
    }
    return acc;
}

// Guard: pure function of counters — identical wherever it is evaluated.
__device__ __forceinline__ int slate_use_primary(
    const unsigned* __restrict__ shardCnt, const unsigned* __restrict__ strictSh,
    int s) {
    unsigned strictTot = 0; bool ovf = false;
    for (int sh = 0; sh < NSH; ++sh) {
        if (shardCnt[(sh * SLATE + s) * 16] > SHCAP) ovf = true;
        strictTot += strictSh[(sh * SLATE + s) * 16];
    }
    return (strictTot >= KSEL) && !ovf;
}

// ===========================================================================
// Kernel 1 (R6): head — mlp + sample + select fused (R5 structure), with the
// MLP memory access rewritten for ILP:
//  - each W-row pulled as 8x-float4 register batches (dot256_f64) instead of
//    a rolled scalar-load loop (R5: 36 VGPR compile -> ~500cy/element serial)
//  - W3 trimmed: block s computes ONLY its 20 outputs (rows s*20..s*20+19)
//    and writes its proto/protof slice; union over blocks = all 100 (ready at
//    the kernel boundary for compact1/rank).
//  - sample keys: 2-doc register batching (10 float4 in flight).
// FMA order & key construction bit-identical to all passing rounds.
// Block 5 zeroes counters (replaces hipMemsetAsync).
// ===========================================================================
__global__ __launch_bounds__(1024) void head_kernel(
    const float* __restrict__ x0, const float* __restrict__ docs,
    const float* __restrict__ W1, const float* __restrict__ b1,
    const float* __restrict__ W2, const float* __restrict__ b2,
    const float* __restrict__ W3, const float* __restrict__ b3,
    double* __restrict__ proto, float* __restrict__ protof,
    unsigned short* __restrict__ Tp2, unsigned short* __restrict__ Tm2,
    unsigned short* __restrict__ Thi, unsigned* __restrict__ zeroBase, int N) {
    const int bid = blockIdx.x, t = threadIdx.x;
    if (bid == SLATE) {                  // zeroing block: no barriers, just exit
        for (int i = t; i < 1360; i += 1024) zeroBase[i] = 0u;
        return;
    }
    __shared__ double xs[DDIM];
    __shared__ double h1[HID];
    __shared__ double h2[HID];
    __shared__ double ps20[DDIM];        // this block's slate protos (20)
    __shared__ unsigned wsum[2][16];

    if (t < DDIM) xs[t] = (double)x0[t];
    __syncthreads();
    if (t < HID) {                       // L1: row = 20 floats = 5 float4
        float w[DDIM];
        load_doc(W1, (size_t)t, w);      // W1 rows are 80B, 16B-aligned
        double acc = 0.0;
#pragma unroll
        for (int i = 0; i < DDIM; ++i) acc = fma(xs[i], (double)w[i], acc);
        acc += (double)b1[t];
        h1[t] = dleaky(acc);
    }
    __syncthreads();
    if (t < HID) {                       // L2: batched row dot
        double acc = dot256_f64(W2 + (size_t)t * HID, h1);
        acc += (double)b2[t];
        h2[t] = dleaky(acc);
    }
    __syncthreads();
    if (t < DDIM) {                      // L3: only this block's 20 outputs
        const int g = bid * DDIM + t;
        double acc = dot256_f64(W3 + (size_t)g * HID, h2);
        acc += (double)b3[g];
        double v = dleaky(acc);
        ps20[t] = v;
        proto[g] = v;                    // each block writes its slice
        protof[g] = (float)v;
    }
    __syncthreads();

    // ---- this slate's 16384 sample keys, 2-doc register batches ----------
    unsigned short kk[16];
#pragma unroll
    for (int j = 0; j < 16; j += 2) {
        int iA = j * 1024 + t, iB = (j + 1) * 1024 + t;
        float dA[DDIM], dB[DDIM];
        bool vA = iA < N, vB = iB < N;
        if (vA) load_doc(docs, (size_t)iA, dA);
        if (vB) load_doc(docs, (size_t)iB, dB);
        unsigned short kA = 0xffffu, kB = 0xffffu;
        if (vA) {
            double d2 = calc_d2(dA, ps20);          // exact f64, same as ever
            kA = (unsigned short)(__float_as_uint((float)d2) >> 16);
        }
        if (vB) {
            double d2 = calc_d2(dB, ps20);
            kB = (unsigned short)(__float_as_uint((float)d2) >> 16);
        }
        kk[j] = kA; kk[j + 1] = kB;
    }

    // ---- dual binary search -> ranks 10 & 100 (identical counting logic) --
    const int lane = t & 63, w = t >> 6;
    unsigned X10 = 0, X100 = 0;
    int buf = 0;
    for (int b = 15; b >= 0; --b) {
        unsigned p10 = X10 | (1u << b), p100 = X100 | (1u << b);
        int c10 = 0, c100 = 0;
#pragma unroll
        for (int j = 0; j < 16; ++j) {
            c10  += ((unsigned)kk[j] < p10);
            c100 += ((unsigned)kk[j] < p100);
        }
#pragma unroll
        for (int off = 32; off; off >>= 1) {
            c10  += __shfl_down(c10, off);
            c100 += __shfl_down(c100, off);
        }
        if (lane == 0) wsum[buf][w] = (unsigned)c10 | ((unsigned)c100 << 16);
        __syncthreads();
        unsigned t10 = 0, t100 = 0;
        for (int i = 0; i < 16; ++i) {
            unsigned v = wsum[buf][i];
            t10 += v & 0xffffu; t100 += v >> 16;
        }
        if ((int)t10 < 10)   X10 = p10;
        if ((int)t100 < 100) X100 = p100;
        buf ^= 1;
    }
    if (t == 0) {
        unsigned tp = X10 + 2u; if (tp > 65535u) tp = 65535u;
        Tp2[bid] = (unsigned short)tp;
        Tm2[bid] = (unsigned short)(X10 >= 2u ? X10 - 2u : 0u);
        Thi[bid] = (unsigned short)X100;   // >=100 docs qualify: the samples themselves
    }
}

// -------- Kernel 2: f32 bulk filter, sharded wave-aggregated atomics --------
// (verbatim from the proven rounds; HBM-bound at ~12.3us floor for 80MB)
__global__ __launch_bounds__(256) void compact1_kernel(
    const float* __restrict__ docs, const float* __restrict__ protof,
    const unsigned short* __restrict__ Tp2, const unsigned short* __restrict__ Tm2,
    unsigned* __restrict__ shardCnt, unsigned* __restrict__ strictSh,
    unsigned* __restrict__ candIdx, int N) {
    __shared__ float psf[SLATE * DDIM];
    __shared__ unsigned short ktp[SLATE], ktm[SLATE];
    int t = threadIdx.x;
    if (t < SLATE * DDIM) psf[t] = protof[t];
    if (t < SLATE) { ktp[t] = Tp2[t]; ktm[t] = Tm2[t]; }
    __syncthreads();

    int n = blockIdx.x * 256 + t;
    bool dv = n < N;               // NO early return: ballots need full wave
    int lane = t & 63;
    int sh = blockIdx.x & (NSH - 1);

    float doc[DDIM];
    if (dv) load_doc(docs, (size_t)n, doc);
    else {
#pragma unroll
        for (int i = 0; i < DDIM; ++i) doc[i] = 0.f;
    }
    float acc[SLATE] = {0.f, 0.f, 0.f, 0.f, 0.f};
#pragma unroll
    for (int i = 0; i < DDIM; ++i) {
        float dvi = doc[i];
#pragma unroll
        for (int s = 0; s < SLATE; ++s) {
            float d = dvi - psf[s * DDIM + i];
            acc[s] = fmaf(d, d, acc[s]);   // f32 FILTER only; f64 redone later
        }
    }
#pragma unroll
    for (int s = 0; s < SLATE; ++s) {
        unsigned k32 = __float_as_uint(acc[s]) >> 16;
        bool hit = dv && k32 <= (unsigned)ktp[s];
        unsigned long long ms = __ballot(dv && k32 <= (unsigned)ktm[s]);
        if (ms) {
            int ldr = __ffsll(ms) - 1;
            if (lane == ldr)
                atomicAdd(&strictSh[(sh * SLATE + s) * 16], (unsigned)__popcll(ms));
        }
        unsigned long long mh = __ballot(hit);
        if (mh) {
            int ldr = __ffsll(mh) - 1;
            unsigned base = 0;
            if (lane == ldr)
                base = atomicAdd(&shardCnt[(sh * SLATE + s) * 16], (unsigned)__popcll(mh));
            base = __shfl(base, ldr);
            if (hit) {
                unsigned pos = base + (unsigned)__popcll(mh & ((1ull << lane) - 1ull));
                if (pos < SHCAP)
                    candIdx[((size_t)(s * NSH + sh)) * SHCAP + pos] = (unsigned)n;
            }
        }
    }
}

// ===========================================================================
// Kernel 3: per-(slate,shard) exact f64 top-100 (40 blocks), with compact2's
// recovery scan folded in. 8-way unrolled rank loop (ILP over LDS latency).
// (verbatim from R4/R5)
// ===========================================================================
__global__ __launch_bounds__(256) void rank_kernel(
    const float* __restrict__ docs, const double* __restrict__ proto,
    const unsigned short* __restrict__ Thi,
    const unsigned* __restrict__ shardCnt, const unsigned* __restrict__ strictSh,
    const unsigned* __restrict__ candIdx, unsigned* __restrict__ rscratch,
    double* __restrict__ stD2, unsigned* __restrict__ stIx,
    unsigned* __restrict__ stLen, int N) {
    const int sh = blockIdx.x, s = blockIdx.y, t = threadIdx.x;
    __shared__ double   ld[SHCAP];
    __shared__ unsigned li[SHCAP];
    __shared__ double   ps[DDIM];
    __shared__ double   outD2[KSEL];
    __shared__ unsigned outIx[KSEL];
    __shared__ unsigned c_s, rcnt;
    __shared__ int      prim_s;

    if (t < DDIM) ps[t] = proto[s * DDIM + t];
    if (t == 0) { prim_s = slate_use_primary(shardCnt, strictSh, s); rcnt = 0u; }
    __syncthreads();

    // ---- gather candidates for this (s,sh) into LDS with exact f64 d2 ----
    unsigned c;
    if (prim_s) {
        if (t == 0) {
            unsigned cc = shardCnt[(sh * SLATE + s) * 16];
            c_s = cc > SHCAP ? SHCAP : cc;          // unreachable clamp (guard)
        }
        __syncthreads();
        c = c_s;
        const unsigned* src = candIdx + ((size_t)(s * NSH + sh)) * SHCAP;
        for (unsigned i = t; i < c; i += 256) {
            unsigned idx = src[i];
            li[i] = idx;
            float doc[DDIM];
            load_doc(docs, (size_t)idx, doc);
            ld[i] = calc_d2(doc, ps);               // canonical exact d2
        }
    } else {
        // exact recovery scan over this block's doc slice
        unsigned kt = Thi[s];
        unsigned* lst = rscratch + (size_t)s * RCAP + (size_t)sh * SHCAP;
        int lo = (int)((long long)N * sh / NSH);
        int hi = (int)((long long)N * (sh + 1) / NSH);
        for (int n = lo + t; n < hi; n += 256) {
            float doc[DDIM];
            load_doc(docs, (size_t)n, doc);
            double d2 = calc_d2(doc, ps);
            unsigned key = __float_as_uint((float)d2) >> 16;
            if (key <= kt) {
                unsigned pos = atomicAdd(&rcnt, 1u);
                if (pos < SHCAP) lst[pos] = (unsigned)n;
            }
        }
        __syncthreads();
        c = rcnt < SHCAP ? rcnt : SHCAP;
        for (unsigned i = t; i < c; i += 256) {
            unsigned idx = lst[i];
            li[i] = idx;
            float doc[DDIM];
            load_doc(docs, (size_t)idx, doc);
            ld[i] = calc_d2(doc, ps);
        }
    }
    __syncthreads();

    // ---- exact local rank by (d2, idx); 8-way unrolled LDS compare loop ----
    for (unsigned e = t; e < c; e += 256) {
        double de = ld[e]; unsigned ie = li[e];
        unsigned rank = 0;
        unsigned j = 0;
        for (; j + 8 <= c; j += 8) {
            double d0 = ld[j+0], d1 = ld[j+1], d2 = ld[j+2], d3 = ld[j+3];
            double d4 = ld[j+4], d5 = ld[j+5], d6 = ld[j+6], d7 = ld[j+7];
            unsigned i0 = li[j+0], i1 = li[j+1], i2 = li[j+2], i3 = li[j+3];
            unsigned i4 = li[j+4], i5 = li[j+5], i6 = li[j+6], i7 = li[j+7];
            rank += ((d0 < de) || (d0 == de && i0 < ie))
                  + ((d1 < de) || (d1 == de && i1 < ie))
                  + ((d2 < de) || (d2 == de && i2 < ie))
                  + ((d3 < de) || (d3 == de && i3 < ie))
                  + ((d4 < de) || (d4 == de && i4 < ie))
                  + ((d5 < de) || (d5 == de && i5 < ie))
                  + ((d6 < de) || (d6 == de && i6 < ie))
                  + ((d7 < de) || (d7 == de && i7 < ie));
        }
        for (; j < c; ++j) {
            double dj = ld[j]; unsigned ij = li[j];
            rank += (dj < de) || (dj == de && ij < ie);
        }
        if (rank < KSEL) { outD2[rank] = de; outIx[rank] = ie; }
    }
    __syncthreads();

    unsigned L = c < KSEL ? c : KSEL;
    size_t base = (size_t)(s * NSH + sh) * STP;
    for (unsigned r = t; r < L; r += 256) {
        stD2[base + r] = outD2[r];
        stIx[base + r] = outIx[r];
    }
    if (t == 0) stLen[s * NSH + sh] = L;
}

// -------- Kernel 4: merge 8 sorted lists, interleaved binary searches -------
// (verbatim from R4/R5)
__global__ __launch_bounds__(1024) void merge_kernel(
    const float* __restrict__ docs,
    const double* __restrict__ stD2, const unsigned* __restrict__ stIx,
    const unsigned* __restrict__ stLen, float* __restrict__ out) {
    int s = blockIdx.x, t = threadIdx.x;
    __shared__ double md[NSH * KSEL];
    __shared__ unsigned mi[NSH * KSEL];
    __shared__ unsigned Ls[NSH], offs[NSH + 1];
    __shared__ unsigned sel[KSEL];
    if (t < NSH) Ls[t] = stLen[s * NSH + t];
    __syncthreads();
    if (t == 0) {
        unsigned o = 0;
        for (int sh = 0; sh < NSH; ++sh) { offs[sh] = o; o += Ls[sh]; }
        offs[NSH] = o;
    }
    __syncthreads();
    for (int sh = 0; sh < NSH; ++sh) {
        unsigned L = Ls[sh];
        for (unsigned i = t; i < L; i += 1024) {
            md[sh * KSEL + i] = stD2[(size_t)(s * NSH + sh) * STP + i];
            mi[sh * KSEL + i] = stIx[(size_t)(s * NSH + sh) * STP + i];
        }
    }
    __syncthreads();

    unsigned S = offs[NSH];
    for (unsigned e = t; e < S; e += 1024) {
        // locate (shard, local pos)
        int sh = 0;
        while (e >= offs[sh + 1]) ++sh;
        unsigned i = e - offs[sh];
        double xd = md[sh * KSEL + i];
        unsigned xi = mi[sh * KSEL + i];
        // interleaved lower_bound by (d2, idx) across the 7 other lists
        unsigned lo[NSH], hi[NSH];
#pragma unroll
        for (int so = 0; so < NSH; ++so) { lo[so] = 0; hi[so] = (so == sh) ? 0u : Ls[so]; }
        bool active = true;
        while (active) {
            active = false;
            double   dj[NSH];
            unsigned ij[NSH], mid[NSH];
#pragma unroll
            for (int so = 0; so < NSH; ++so) {
                if (lo[so] < hi[so]) {
                    unsigned m = (lo[so] + hi[so]) >> 1;
                    mid[so] = m;
                    dj[so] = md[so * KSEL + m];     // independent loads, pipelined
                    ij[so] = mi[so * KSEL + m];
                }
            }
#pragma unroll
            for (int so = 0; so < NSH; ++so) {
                if (lo[so] < hi[so]) {
                    bool less = (dj[so] < xd) || (dj[so] == xd && ij[so] < xi);
                    if (less) lo[so] = mid[so] + 1; else hi[so] = mid[so];
                    if (lo[so] < hi[so]) active = true;
                }
            }
        }
        unsigned rank = i;                        // own sorted list: i smaller
#pragma unroll
        for (int so = 0; so < NSH; ++so) rank += lo[so];
        if (rank < KSEL) sel[rank] = xi;
    }
    __syncthreads();

    if (t < KSEL) out[(size_t)OUT_IDX_OFF + s * KSEL + t] = (float)sel[t];
    for (int pos = t; pos < KSEL * DDIM; pos += 1024) {
        int r = pos / DDIM, c = pos % DDIM;
        out[((size_t)s * KSEL + r) * DDIM + c] = docs[(size_t)sel[r] * DDIM + c];
    }
}

extern "C" void kernel_launch(void* const* d_in, const int* in_sizes, int n_in,
                              void* d_out, int out_size, void* d_ws, size_t ws_size,
                              hipStream_t stream) {
    const float* x0   = (const float*)d_in[0];
    const float* docs = (const float*)d_in[1];
    const float* W1   = (const float*)d_in[2];
    const float* b1   = (const float*)d_in[3];
    const float* W2   = (const float*)d_in[4];
    const float* b2   = (const float*)d_in[5];
    const float* W3   = (const float*)d_in[6];
    const float* b3   = (const float*)d_in[7];
    int N = in_sizes[1] / DDIM;   // 1,000,000

    char* ws = (char*)d_ws;
    double*         proto    = (double*)(ws + WS_PROTO);
    float*          protof   = (float*)(ws + WS_PROTOF);
    unsigned short* Tp2      = (unsigned short*)(ws + WS_TP2);
    unsigned short* Tm2      = (unsigned short*)(ws + WS_TM2);
    unsigned short* Thi      = (unsigned short*)(ws + WS_THI);
    unsigned*       shardCnt = (unsigned*)(ws + WS_SHCNT);
    unsigned*       strictSh = (unsigned*)(ws + WS_STRICT);
    unsigned*       candIdx  = (unsigned*)(ws + WS_CAND);
    unsigned*       rscratch = (unsigned*)(ws + WS_CAND2);
    double*         stD2     = (double*)(ws + WS_STD2);
    unsigned*       stIx     = (unsigned*)(ws + WS_STIX);
    unsigned*       stLen    = (unsigned*)(ws + WS_STLEN);
    float*          outp     = (float*)d_out;

    // 4 kernels / 3 boundaries. No cooperative launch (R1: grid.sync ~100us),
    // no device-scope fences (R3: L2 writeback tens of us), no hipMemsetAsync
    // (zeroing fused), no skeys round-trip (R5), MLP loads batched (R6).
    head_kernel<<<SLATE + 1, 1024, 0, stream>>>(
        x0, docs, W1, b1, W2, b2, W3, b3, proto, protof,
        Tp2, Tm2, Thi, shardCnt, N);
    int nb = (N + 255) / 256;
    compact1_kernel<<<nb, 256, 0, stream>>>(docs, protof, Tp2, Tm2,
                                            shardCnt, strictSh, candIdx, N);
    rank_kernel<<<dim3(NSH, SLATE), 256, 0, stream>>>(
        docs, proto, Thi, shardCnt, strictSh, candIdx, rscratch,
        stD2, stIx, stLen, N);
    merge_kernel<<<SLATE, 1024, 0, stream>>>(docs, stD2, stIx, stLen, outp);
}

// Round 7
// 97.626 us; speedup vs baseline: 1.0489x; 1.0489x over previous
//
#include <hip/hip_runtime.h>
#include <stdint.h>
#include <math.h>

// Problem constants (fixed by the reference)
#define DDIM    20
#define SLATE   5
#define KSEL    100
#define HID     256
#define SAMPN   16384                // prefix-sample size (docs are iid)
#define NSH     8                    // atomic shards
#define SHCAP   1024                 // per-shard candidate capacity
#define RCAP    8192                 // recovery scratch per slate (8 slices x 1024)
#define STP     128                  // shard-top stride (pad of KSEL)
#define HEADT   512                  // head block size (R6 lesson: 1024-thr caps VGPR at 64 -> spills)
#define OUT_IDX_OFF (SLATE * KSEL * DDIM)   // 10000

// Workspace byte offsets
#define WS_PROTO   0                 // f64[100]
#define WS_PROTOF  1024              // f32[100]
#define WS_TP2     1536              // u16[5]  T10+2
#define WS_TM2     1556              // u16[5]  T10-2
#define WS_THI     1576              // u16[5]  sample rank-100 key
#define WS_SHCNT   1600              // u32[40] stride-16 (64B lines)  <- zeroed in head
#define WS_STRICT  4160              // u32[40] stride-16              <- zeroed
#define WS_CNT2    6720              // u32[5]  stride-16 (unused)     <- zeroed
#define WS_ZEND    7040              // end of zeroed region
#define WS_CAND    172032            // u32[5][NSH][SHCAP]           -> 335872
#define WS_CAND2   335872            // u32[5][NSH][1024] recovery   -> 499712
#define WS_STD2    499712            // f64[5][NSH][STP]             -> 540672
#define WS_STIX    540672            // u32[5][NSH][STP]             -> 561152
#define WS_STLEN   561152            // u32[5][NSH]                  -> 561312

// ---- exact-order f64 distance: UNCHANGED from all passing rounds ----
__device__ __forceinline__ double dleaky(double x) { return x >= 0.0 ? x : 0.01 * x; }

__device__ __forceinline__ double calc_d2(const float* doc, const double* p) {
    double acc = 0.0;
#pragma unroll
    for (int i = 0; i < DDIM; ++i) {
        double d = (double)doc[i] - p[i];
        acc = fma(d, d, acc);
    }
    return acc;
}

__device__ __forceinline__ void load_doc(const float* __restrict__ docs,
                                         size_t n, float* doc) {
    const float4* dp = (const float4*)(docs + n * DDIM);
    float4 v0 = dp[0], v1 = dp[1], v2 = dp[2], v3 = dp[3], v4 = dp[4];
    doc[0] = v0.x; doc[1] = v0.y; doc[2] = v0.z; doc[3] = v0.w;
    doc[4] = v1.x; doc[5] = v1.y; doc[6] = v1.z; doc[7] = v1.w;
    doc[8] = v2.x; doc[9] = v2.y; doc[10] = v2.z; doc[11] = v2.w;
    doc[12] = v3.x; doc[13] = v3.y; doc[14] = v3.z; doc[15] = v3.w;
    doc[16] = v4.x; doc[17] = v4.y; doc[18] = v4.z; doc[19] = v4.w;
}

// Row-dot in f64, 8x-float4 load batches; FMA order i=0..255 ascending —
// bit-identical to all passing rounds. (Passed in R6.)
__device__ __forceinline__ double dot256_f64(const float* __restrict__ Wrow,
                                             const double* __restrict__ h) {
    const float4* wr = (const float4*)Wrow;     // row is 1KB, 16B-aligned
    double acc = 0.0;
#pragma unroll
    for (int b = 0; b < 8; ++b) {
        float4 v[8];
#pragma unroll
        for (int u = 0; u < 8; ++u) v[u] = wr[b * 8 + u];   // 8 independent loads
#pragma unroll
        for (int u = 0; u < 8; ++u) {
            const int i = (b * 8 + u) * 4;
            acc = fma(h[i + 0], (double)v[u].x, acc);
            acc = fma(h[i + 1], (double)v[u].y, acc);
            acc = fma(h[i + 2], (double)v[u].z, acc);
            acc = fma(h[i + 3], (double)v[u].w, acc);
        }
    }
    return acc;
}

// Guard: pure function of counters — identical wherever it is evaluated.
__device__ __forceinline__ int slate_use_primary(
    const unsigned* __restrict__ shardCnt, const unsigned* __restrict__ strictSh,
    int s) {
    unsigned strictTot = 0; bool ovf = false;
    for (int sh = 0; sh < NSH; ++sh) {
        if (shardCnt[(sh * SLATE + s) * 16] > SHCAP) ovf = true;
        strictTot += strictSh[(sh * SLATE + s) * 16];
    }
    return (strictTot >= KSEL) && !ovf;
}

// ===========================================================================
// Kernel 1 (R7): head — mlp + sample + select fused, spill-free this time.
// R6 post-mortem: __launch_bounds__(1024) caps VGPR at 64 -> the 16-key +
// 2-doc register state spilled to scratch -> 58us at 0.8% occupancy with the
// cost present even fully-cached (replay _ord302: 58us @ 109KB HBM).
// Fix: 512 threads (proper VGPR budget, 8 waves of latency hiding) and the
// 16384 sample keys live in LDS (32KB), not registers — per-thread live
// state is ONE 20-float doc. The dual binary search reads keys back as
// packed u32 (coalesced ds_read_b32, 2-lane/bank aliasing = free).
// MLP (trimmed W3, passed in R6), key construction, and the count-based
// threshold search are bit-identical to all passing rounds.
// Block 5 zeroes counters (replaces hipMemsetAsync).
// ===========================================================================
__global__ __launch_bounds__(HEADT) void head_kernel(
    const float* __restrict__ x0, const float* __restrict__ docs,
    const float* __restrict__ W1, const float* __restrict__ b1,
    const float* __restrict__ W2, const float* __restrict__ b2,
    const float* __restrict__ W3, const float* __restrict__ b3,
    double* __restrict__ proto, float* __restrict__ protof,
    unsigned short* __restrict__ Tp2, unsigned short* __restrict__ Tm2,
    unsigned short* __restrict__ Thi, unsigned* __restrict__ zeroBase, int N) {
    const int bid = blockIdx.x, t = threadIdx.x;
    if (bid == SLATE) {                  // zeroing block: no barriers, just exit
        for (int i = t; i < 1360; i += HEADT) zeroBase[i] = 0u;
        return;
    }
    __shared__ double xs[DDIM];
    __shared__ double h1[HID];
    __shared__ double h2[HID];
    __shared__ double ps20[DDIM];            // this block's slate protos (20)
    __shared__ unsigned short kls[SAMPN];    // 32KB: this slate's sample keys
    __shared__ unsigned wsum[2][HEADT / 64];

    // ---- f64 MLP (bit-identical order; threads >= HID idle per layer) -----
    if (t < DDIM) xs[t] = (double)x0[t];
    __syncthreads();
    if (t < HID) {                       // L1: row = 20 floats = 5 float4
        float w[DDIM];
        load_doc(W1, (size_t)t, w);      // W1 rows are 80B, 16B-aligned
        double acc = 0.0;
#pragma unroll
        for (int i = 0; i < DDIM; ++i) acc = fma(xs[i], (double)w[i], acc);
        acc += (double)b1[t];
        h1[t] = dleaky(acc);
    }
    __syncthreads();
    if (t < HID) {                       // L2: batched row dot
        double acc = dot256_f64(W2 + (size_t)t * HID, h1);
        acc += (double)b2[t];
        h2[t] = dleaky(acc);
    }
    __syncthreads();
    if (t < DDIM) {                      // L3: only this block's 20 outputs
        const int g = bid * DDIM + t;
        double acc = dot256_f64(W3 + (size_t)g * HID, h2);
        acc += (double)b3[g];
        double v = dleaky(acc);
        ps20[t] = v;
        proto[g] = v;                    // each block writes its slice
        protof[g] = (float)v;
    }
    __syncthreads();

    // ---- this slate's 16384 sample keys -> LDS (1 doc live per thread) ----
    for (int chunk = 0; chunk < SAMPN / HEADT; ++chunk) {
        int i = chunk * HEADT + t;                 // coalesced doc rows
        unsigned short key = 0xffffu;
        if (i < N) {
            float doc[DDIM];
            load_doc(docs, (size_t)i, doc);
            double d2 = calc_d2(doc, ps20);        // exact f64, same as ever
            key = (unsigned short)(__float_as_uint((float)d2) >> 16);
        }
        kls[i] = key;
    }
    __syncthreads();

    // ---- dual binary search -> ranks 10 & 100 (identical counting logic) --
    const unsigned* kls32 = (const unsigned*)kls;  // 2 keys per word
    const int lane = t & 63, w = t >> 6;
    unsigned X10 = 0, X100 = 0;
    int buf = 0;
    for (int b = 15; b >= 0; --b) {
        unsigned p10 = X10 | (1u << b), p100 = X100 | (1u << b);
        int c10 = 0, c100 = 0;
#pragma unroll
        for (int j = 0; j < SAMPN / 2 / HEADT; ++j) {   // 16 packed words
            unsigned kw = kls32[j * HEADT + t];         // coalesced LDS read
            unsigned lo = kw & 0xffffu, hi = kw >> 16;
            c10  += (lo < p10)  + (hi < p10);
            c100 += (lo < p100) + (hi < p100);
        }
#pragma unroll
        for (int off = 32; off; off >>= 1) {
            c10  += __shfl_down(c10, off);
            c100 += __shfl_down(c100, off);
        }
        if (lane == 0) wsum[buf][w] = (unsigned)c10 | ((unsigned)c100 << 16);
        __syncthreads();
        unsigned t10 = 0, t100 = 0;
        for (int i = 0; i < HEADT / 64; ++i) {
            unsigned v = wsum[buf][i];
            t10 += v & 0xffffu; t100 += v >> 16;
        }
        if ((int)t10 < 10)   X10 = p10;
        if ((int)t100 < 100) X100 = p100;
        buf ^= 1;
    }
    if (t == 0) {
        unsigned tp = X10 + 2u; if (tp > 65535u) tp = 65535u;
        Tp2[bid] = (unsigned short)tp;
        Tm2[bid] = (unsigned short)(X10 >= 2u ? X10 - 2u : 0u);
        Thi[bid] = (unsigned short)X100;   // >=100 docs qualify: the samples themselves
    }
}

// -------- Kernel 2: f32 bulk filter, sharded wave-aggregated atomics --------
// (verbatim from the proven rounds; HBM-bound at ~12.3us floor for 80MB)
__global__ __launch_bounds__(256) void compact1_kernel(
    const float* __restrict__ docs, const float* __restrict__ protof,
    const unsigned short* __restrict__ Tp2, const unsigned short* __restrict__ Tm2,
    unsigned* __restrict__ shardCnt, unsigned* __restrict__ strictSh,
    unsigned* __restrict__ candIdx, int N) {
    __shared__ float psf[SLATE * DDIM];
    __shared__ unsigned short ktp[SLATE], ktm[SLATE];
    int t = threadIdx.x;
    if (t < SLATE * DDIM) psf[t] = protof[t];
    if (t < SLATE) { ktp[t] = Tp2[t]; ktm[t] = Tm2[t]; }
    __syncthreads();

    int n = blockIdx.x * 256 + t;
    bool dv = n < N;               // NO early return: ballots need full wave
    int lane = t & 63;
    int sh = blockIdx.x & (NSH - 1);

    float doc[DDIM];
    if (dv) load_doc(docs, (size_t)n, doc);
    else {
#pragma unroll
        for (int i = 0; i < DDIM; ++i) doc[i] = 0.f;
    }
    float acc[SLATE] = {0.f, 0.f, 0.f, 0.f, 0.f};
#pragma unroll
    for (int i = 0; i < DDIM; ++i) {
        float dvi = doc[i];
#pragma unroll
        for (int s = 0; s < SLATE; ++s) {
            float d = dvi - psf[s * DDIM + i];
            acc[s] = fmaf(d, d, acc[s]);   // f32 FILTER only; f64 redone later
        }
    }
#pragma unroll
    for (int s = 0; s < SLATE; ++s) {
        unsigned k32 = __float_as_uint(acc[s]) >> 16;
        bool hit = dv && k32 <= (unsigned)ktp[s];
        unsigned long long ms = __ballot(dv && k32 <= (unsigned)ktm[s]);
        if (ms) {
            int ldr = __ffsll(ms) - 1;
            if (lane == ldr)
                atomicAdd(&strictSh[(sh * SLATE + s) * 16], (unsigned)__popcll(ms));
        }
        unsigned long long mh = __ballot(hit);
        if (mh) {
            int ldr = __ffsll(mh) - 1;
            unsigned base = 0;
            if (lane == ldr)
                base = atomicAdd(&shardCnt[(sh * SLATE + s) * 16], (unsigned)__popcll(mh));
            base = __shfl(base, ldr);
            if (hit) {
                unsigned pos = base + (unsigned)__popcll(mh & ((1ull << lane) - 1ull));
                if (pos < SHCAP)
                    candIdx[((size_t)(s * NSH + sh)) * SHCAP + pos] = (unsigned)n;
            }
        }
    }
}

// ===========================================================================
// Kernel 3: per-(slate,shard) exact f64 top-100 (40 blocks), with compact2's
// recovery scan folded in. 8-way unrolled rank loop (ILP over LDS latency).
// (verbatim from R4/R5/R6)
// ===========================================================================
__global__ __launch_bounds__(256) void rank_kernel(
    const float* __restrict__ docs, const double* __restrict__ proto,
    const unsigned short* __restrict__ Thi,
    const unsigned* __restrict__ shardCnt, const unsigned* __restrict__ strictSh,
    const unsigned* __restrict__ candIdx, unsigned* __restrict__ rscratch,
    double* __restrict__ stD2, unsigned* __restrict__ stIx,
    unsigned* __restrict__ stLen, int N) {
    const int sh = blockIdx.x, s = blockIdx.y, t = threadIdx.x;
    __shared__ double   ld[SHCAP];
    __shared__ unsigned li[SHCAP];
    __shared__ double   ps[DDIM];
    __shared__ double   outD2[KSEL];
    __shared__ unsigned outIx[KSEL];
    __shared__ unsigned c_s, rcnt;
    __shared__ int      prim_s;

    if (t < DDIM) ps[t] = proto[s * DDIM + t];
    if (t == 0) { prim_s = slate_use_primary(shardCnt, strictSh, s); rcnt = 0u; }
    __syncthreads();

    // ---- gather candidates for this (s,sh) into LDS with exact f64 d2 ----
    unsigned c;
    if (prim_s) {
        if (t == 0) {
            unsigned cc = shardCnt[(sh * SLATE + s) * 16];
            c_s = cc > SHCAP ? SHCAP : cc;          // unreachable clamp (guard)
        }
        __syncthreads();
        c = c_s;
        const unsigned* src = candIdx + ((size_t)(s * NSH + sh)) * SHCAP;
        for (unsigned i = t; i < c; i += 256) {
            unsigned idx = src[i];
            li[i] = idx;
            float doc[DDIM];
            load_doc(docs, (size_t)idx, doc);
            ld[i] = calc_d2(doc, ps);               // canonical exact d2
        }
    } else {
        // exact recovery scan over this block's doc slice
        unsigned kt = Thi[s];
        unsigned* lst = rscratch + (size_t)s * RCAP + (size_t)sh * SHCAP;
        int lo = (int)((long long)N * sh / NSH);
        int hi = (int)((long long)N * (sh + 1) / NSH);
        for (int n = lo + t; n < hi; n += 256) {
            float doc[DDIM];
            load_doc(docs, (size_t)n, doc);
            double d2 = calc_d2(doc, ps);
            unsigned key = __float_as_uint((float)d2) >> 16;
            if (key <= kt) {
                unsigned pos = atomicAdd(&rcnt, 1u);
                if (pos < SHCAP) lst[pos] = (unsigned)n;
            }
        }
        __syncthreads();
        c = rcnt < SHCAP ? rcnt : SHCAP;
        for (unsigned i = t; i < c; i += 256) {
            unsigned idx = lst[i];
            li[i] = idx;
            float doc[DDIM];
            load_doc(docs, (size_t)idx, doc);
            ld[i] = calc_d2(doc, ps);
        }
    }
    __syncthreads();

    // ---- exact local rank by (d2, idx); 8-way unrolled LDS compare loop ----
    for (unsigned e = t; e < c; e += 256) {
        double de = ld[e]; unsigned ie = li[e];
        unsigned rank = 0;
        unsigned j = 0;
        for (; j + 8 <= c; j += 8) {
            double d0 = ld[j+0], d1 = ld[j+1], d2 = ld[j+2], d3 = ld[j+3];
            double d4 = ld[j+4], d5 = ld[j+5], d6 = ld[j+6], d7 = ld[j+7];
            unsigned i0 = li[j+0], i1 = li[j+1], i2 = li[j+2], i3 = li[j+3];
            unsigned i4 = li[j+4], i5 = li[j+5], i6 = li[j+6], i7 = li[j+7];
            rank += ((d0 < de) || (d0 == de && i0 < ie))
                  + ((d1 < de) || (d1 == de && i1 < ie))
                  + ((d2 < de) || (d2 == de && i2 < ie))
                  + ((d3 < de) || (d3 == de && i3 < ie))
                  + ((d4 < de) || (d4 == de && i4 < ie))
                  + ((d5 < de) || (d5 == de && i5 < ie))
                  + ((d6 < de) || (d6 == de && i6 < ie))
                  + ((d7 < de) || (d7 == de && i7 < ie));
        }
        for (; j < c; ++j) {
            double dj = ld[j]; unsigned ij = li[j];
            rank += (dj < de) || (dj == de && ij < ie);
        }
        if (rank < KSEL) { outD2[rank] = de; outIx[rank] = ie; }
    }
    __syncthreads();

    unsigned L = c < KSEL ? c : KSEL;
    size_t base = (size_t)(s * NSH + sh) * STP;
    for (unsigned r = t; r < L; r += 256) {
        stD2[base + r] = outD2[r];
        stIx[base + r] = outIx[r];
    }
    if (t == 0) stLen[s * NSH + sh] = L;
}

// -------- Kernel 4: merge 8 sorted lists, interleaved binary searches -------
// (verbatim from R4/R5/R6)
__global__ __launch_bounds__(1024) void merge_kernel(
    const float* __restrict__ docs,
    const double* __restrict__ stD2, const unsigned* __restrict__ stIx,
    const unsigned* __restrict__ stLen, float* __restrict__ out) {
    int s = blockIdx.x, t = threadIdx.x;
    __shared__ double md[NSH * KSEL];
    __shared__ unsigned mi[NSH * KSEL];
    __shared__ unsigned Ls[NSH], offs[NSH + 1];
    __shared__ unsigned sel[KSEL];
    if (t < NSH) Ls[t] = stLen[s * NSH + t];
    __syncthreads();
    if (t == 0) {
        unsigned o = 0;
        for (int sh = 0; sh < NSH; ++sh) { offs[sh] = o; o += Ls[sh]; }
        offs[NSH] = o;
    }
    __syncthreads();
    for (int sh = 0; sh < NSH; ++sh) {
        unsigned L = Ls[sh];
        for (unsigned i = t; i < L; i += 1024) {
            md[sh * KSEL + i] = stD2[(size_t)(s * NSH + sh) * STP + i];
            mi[sh * KSEL + i] = stIx[(size_t)(s * NSH + sh) * STP + i];
        }
    }
    __syncthreads();

    unsigned S = offs[NSH];
    for (unsigned e = t; e < S; e += 1024) {
        // locate (shard, local pos)
        int sh = 0;
        while (e >= offs[sh + 1]) ++sh;
        unsigned i = e - offs[sh];
        double xd = md[sh * KSEL + i];
        unsigned xi = mi[sh * KSEL + i];
        // interleaved lower_bound by (d2, idx) across the 7 other lists
        unsigned lo[NSH], hi[NSH];
#pragma unroll
        for (int so = 0; so < NSH; ++so) { lo[so] = 0; hi[so] = (so == sh) ? 0u : Ls[so]; }
        bool active = true;
        while (active) {
            active = false;
            double   dj[NSH];
            unsigned ij[NSH], mid[NSH];
#pragma unroll
            for (int so = 0; so < NSH; ++so) {
                if (lo[so] < hi[so]) {
                    unsigned m = (lo[so] + hi[so]) >> 1;
                    mid[so] = m;
                    dj[so] = md[so * KSEL + m];     // independent loads, pipelined
                    ij[so] = mi[so * KSEL + m];
                }
            }
#pragma unroll
            for (int so = 0; so < NSH; ++so) {
                if (lo[so] < hi[so]) {
                    bool less = (dj[so] < xd) || (dj[so] == xd && ij[so] < xi);
                    if (less) lo[so] = mid[so] + 1; else hi[so] = mid[so];
                    if (lo[so] < hi[so]) active = true;
                }
            }
        }
        unsigned rank = i;                        // own sorted list: i smaller
#pragma unroll
        for (int so = 0; so < NSH; ++so) rank += lo[so];
        if (rank < KSEL) sel[rank] = xi;
    }
    __syncthreads();

    if (t < KSEL) out[(size_t)OUT_IDX_OFF + s * KSEL + t] = (float)sel[t];
    for (int pos = t; pos < KSEL * DDIM; pos += 1024) {
        int r = pos / DDIM, c = pos % DDIM;
        out[((size_t)s * KSEL + r) * DDIM + c] = docs[(size_t)sel[r] * DDIM + c];
    }
}

extern "C" void kernel_launch(void* const* d_in, const int* in_sizes, int n_in,
                              void* d_out, int out_size, void* d_ws, size_t ws_size,
                              hipStream_t stream) {
    const float* x0   = (const float*)d_in[0];
    const float* docs = (const float*)d_in[1];
    const float* W1   = (const float*)d_in[2];
    const float* b1   = (const float*)d_in[3];
    const float* W2   = (const float*)d_in[4];
    const float* b2   = (const float*)d_in[5];
    const float* W3   = (const float*)d_in[6];
    const float* b3   = (const float*)d_in[7];
    int N = in_sizes[1] / DDIM;   // 1,000,000

    char* ws = (char*)d_ws;
    double*         proto    = (double*)(ws + WS_PROTO);
    float*          protof   = (float*)(ws + WS_PROTOF);
    unsigned short* Tp2      = (unsigned short*)(ws + WS_TP2);
    unsigned short* Tm2      = (unsigned short*)(ws + WS_TM2);
    unsigned short* Thi      = (unsigned short*)(ws + WS_THI);
    unsigned*       shardCnt = (unsigned*)(ws + WS_SHCNT);
    unsigned*       strictSh = (unsigned*)(ws + WS_STRICT);
    unsigned*       candIdx  = (unsigned*)(ws + WS_CAND);
    unsigned*       rscratch = (unsigned*)(ws + WS_CAND2);
    double*         stD2     = (double*)(ws + WS_STD2);
    unsigned*       stIx     = (unsigned*)(ws + WS_STIX);
    unsigned*       stLen    = (unsigned*)(ws + WS_STLEN);
    float*          outp     = (float*)d_out;

    // 4 kernels / 3 boundaries. No cooperative launch (R1: grid.sync ~100us),
    // no device-scope fences (R3), no hipMemsetAsync (zeroing fused), no
    // skeys global round-trip (R5), head spill-free at 512 threads w/ LDS
    // keys (R7, after R6's VGPR-cap diagnosis).
    head_kernel<<<SLATE + 1, HEADT, 0, stream>>>(
        x0, docs, W1, b1, W2, b2, W3, b3, proto, protof,
        Tp2, Tm2, Thi, shardCnt, N);
    int nb = (N + 255) / 256;
    compact1_kernel<<<nb, 256, 0, stream>>>(docs, protof, Tp2, Tm2,
                                            shardCnt, strictSh, candIdx, N);
    rank_kernel<<<dim3(NSH, SLATE), 256, 0, stream>>>(
        docs, proto, Thi, shardCnt, strictSh, candIdx, rscratch,
        stD2, stIx, stLen, N);
    merge_kernel<<<SLATE, 1024, 0, stream>>>(docs, stD2, stIx, stLen, outp);
}